// Round 10
// baseline (102.712 us; speedup 1.0000x reference)
//
#include <hip/hip_runtime.h>

// Problem constants
constexpr int N = 8192;
constexpr int C = 2048;
constexpr int ND = N + 4;                       // 8196
constexpr size_t XNEW_ELEMS = (size_t)ND * C;   // 16785408
constexpr unsigned TOTAL4 = (unsigned)((size_t)ND * ND / 4);  // 16,793,604

#define C_DIAG 0.5f
#define C_LINK 0.015609764f                     /* 1/sqrt(2*2052) */
#define C_BLK  (1.0f / 2052.0f)

typedef float f32x4 __attribute__((ext_vector_type(4)));

// ---------------------------------------------------------------------------
// Pure zero-fill of adj, maximally fill-like: 4096 blocks x 256 threads =
// 1,048,576 threads; each does 16 UNROLLED f32x4 stores at compile-time
// stride offsets (16 x 1,048,576 = 16,777,216 chunks) + one guarded tail
// store (16,388 remaining). No division, no loop-carried overhead, no value
// computation -- isolates the raw shader store rate vs the runtime fill.
__global__ __launch_bounds__(256) void k_fill0(float* __restrict__ adj) {
    const unsigned base = blockIdx.x * 256u + threadIdx.x;   // < 1048576
    f32x4* __restrict__ p = reinterpret_cast<f32x4*>(adj) + base;
    f32x4 z;
    z.x = 0.0f; z.y = 0.0f; z.z = 0.0f; z.w = 0.0f;
#pragma unroll
    for (int k = 0; k < 16; ++k)
        p[(size_t)k * 1048576u] = z;
    if (base < TOTAL4 - 16u * 1048576u)                      // 16388 tail chunks
        p[(size_t)16 * 1048576u] = z;
}

// ---------------------------------------------------------------------------
// Scatter adj nonzeros (after the bulk zero). ~16400 threads, ~3 us.
__global__ __launch_bounds__(256) void k_adj_nz(float* __restrict__ adj) {
    const int t = blockIdx.x * 256 + threadIdx.x;
    if (t < N) {
        adj[(size_t)t * ND + t] = C_DIAG;                 // diagonal
        adj[(size_t)t * ND + N + (t >> 11)] = C_LINK;     // row -> its center
    } else if (t < N + 4 * 2052) {
        const int u = t - N;
        const int i = u / 2052;                           // center index 0..3
        const int j = u - i * 2052;
        const size_t rowb = (size_t)(N + i) * ND;
        if (j < 2048) adj[rowb + i * 2048 + j] = C_LINK;  // center -> segment
        else          adj[rowb + N + (j - 2048)] = C_BLK; // 4x4 center block
    }
}

// ---------------------------------------------------------------------------
// Attention pass — R2's proven shape verbatim: 512 blocks, 16 rows/block,
// 4 rows/wave, LDS block-combine -> part[block][C] (+ wpart[block]).
template <bool USE_WS>
__global__ __launch_bounds__(256) void k_att(const float* __restrict__ x,
                                             const float* __restrict__ attw,
                                             const float* __restrict__ attb,
                                             float* __restrict__ xnew,
                                             float* __restrict__ part,
                                             float* __restrict__ wpart) {
    __shared__ float lnum[4][C];               // 32 KiB per-wave partials
    __shared__ float lw[4];

    const int tid  = threadIdx.x;
    const int wave = tid >> 6;
    const int lane = tid & 63;
    const int row0 = blockIdx.x * 16;
    const int seg  = blockIdx.x >> 7;          // 128 blocks per segment
    const float bias = attb[0];

    f32x4 wv[8];
#pragma unroll
    for (int q = 0; q < 8; ++q)
        wv[q] = reinterpret_cast<const f32x4*>(attw)[lane + 64 * q];

    float acc[32];
#pragma unroll
    for (int k = 0; k < 32; ++k) acc[k] = 0.0f;
    float wacc = 0.0f;

    for (int r = 0; r < 4; ++r) {
        const int row = row0 + wave * 4 + r;
        const f32x4* xrow = reinterpret_cast<const f32x4*>(x + (size_t)row * C);
        f32x4* orow = reinterpret_cast<f32x4*>(xnew + (size_t)row * C);

        f32x4 xv[8];
        float dot = 0.0f;
#pragma unroll
        for (int q = 0; q < 8; ++q) {
            xv[q] = xrow[lane + 64 * q];
            dot += xv[q].x * wv[q].x + xv[q].y * wv[q].y +
                   xv[q].z * wv[q].z + xv[q].w * wv[q].w;
        }
#pragma unroll
        for (int off = 32; off > 0; off >>= 1) dot += __shfl_xor(dot, off, 64);
        const float wrow = dot + bias;
        wacc += wrow;
#pragma unroll
        for (int q = 0; q < 8; ++q) {
            acc[4 * q + 0] += wrow * xv[q].x;
            acc[4 * q + 1] += wrow * xv[q].y;
            acc[4 * q + 2] += wrow * xv[q].z;
            acc[4 * q + 3] += wrow * xv[q].w;
            orow[lane + 64 * q] = xv[q];       // x_new head copy
        }
    }

#pragma unroll
    for (int q = 0; q < 8; ++q) {
        f32x4 s;
        s.x = acc[4 * q];     s.y = acc[4 * q + 1];
        s.z = acc[4 * q + 2]; s.w = acc[4 * q + 3];
        reinterpret_cast<f32x4*>(&lnum[wave][0])[lane + 64 * q] = s;
    }
    if (lane == 0) lw[wave] = wacc;            // wacc is wave-uniform
    __syncthreads();

    const f32x4* l0 = reinterpret_cast<const f32x4*>(&lnum[0][0]);
    const f32x4* l1 = reinterpret_cast<const f32x4*>(&lnum[1][0]);
    const f32x4* l2 = reinterpret_cast<const f32x4*>(&lnum[2][0]);
    const f32x4* l3 = reinterpret_cast<const f32x4*>(&lnum[3][0]);
#pragma unroll
    for (int c4 = tid; c4 < C / 4; c4 += 256) {
        f32x4 s = l0[c4] + l1[c4] + l2[c4] + l3[c4];
        if constexpr (USE_WS) {
            reinterpret_cast<f32x4*>(part + (size_t)blockIdx.x * C)[c4] = s;
        } else {
            float* dst = &xnew[(size_t)(N + seg) * C + 4 * c4];
            atomicAdd(dst + 0, s.x); atomicAdd(dst + 1, s.y);
            atomicAdd(dst + 2, s.z); atomicAdd(dst + 3, s.w);
        }
    }
    if (tid == 0) {
        const float wb = lw[0] + lw[1] + lw[2] + lw[3];
        if constexpr (USE_WS) wpart[blockIdx.x] = wb;
        else                  atomicAdd(&wpart[seg], wb);
    }
}

// ---------------------------------------------------------------------------
// centers[seg][c] = sum_k part[seg*128+k][c] / sum_k wpart[seg*128+k]
__global__ __launch_bounds__(256) void k_centers(const float* __restrict__ part,
                                                 const float* __restrict__ wpart,
                                                 float* __restrict__ xnew) {
    const int idx = blockIdx.x * 256 + threadIdx.x;   // 0..8191
    const int seg = idx >> 11;
    const int c   = idx & 2047;
    float wsum = 0.0f;
#pragma unroll 8
    for (int k = 0; k < 128; ++k) wsum += wpart[seg * 128 + k];
    float s = 0.0f;
#pragma unroll 8
    for (int k = 0; k < 128; ++k) s += part[(size_t)(seg * 128 + k) * C + c];
    xnew[(size_t)(N + seg) * C + c] = s / wsum;
}

// ---------------------------------------------------------------------------
// Fallback-path helpers (used only if ws is tiny): zero + divide.
__global__ __launch_bounds__(256) void k_zero(float* __restrict__ xnew,
                                              float* __restrict__ wseg) {
    int idx = blockIdx.x * 256 + threadIdx.x;
    if (idx < 4 * C) xnew[(size_t)N * C + idx] = 0.0f;
    if (idx < 4) wseg[idx] = 0.0f;
}
__global__ __launch_bounds__(256) void k_div(float* __restrict__ xnew,
                                             const float* __restrict__ wseg) {
    int idx = blockIdx.x * 256 + threadIdx.x;
    if (idx < 4 * C) xnew[(size_t)N * C + idx] /= wseg[idx >> 11];
}

// ---------------------------------------------------------------------------
extern "C" void kernel_launch(void* const* d_in, const int* in_sizes, int n_in,
                              void* d_out, int out_size, void* d_ws, size_t ws_size,
                              hipStream_t stream) {
    const float* x    = (const float*)d_in[0];
    const float* attw = (const float*)d_in[1];
    const float* attb = (const float*)d_in[2];
    float* xnew = (float*)d_out;                   // [8196, 2048]
    float* adj  = (float*)d_out + XNEW_ELEMS;      // [8196, 8196]

    // adj: our own lean zero-fill (replaces in-graph hipMemsetAsync), then
    // the proven nonzero scatter.
    k_fill0<<<4096, 256, 0, stream>>>(adj);
    k_adj_nz<<<(N + 4 * 2052 + 255) / 256, 256, 0, stream>>>(adj);

    const size_t ws_need = (1024 + (size_t)512 * C) * sizeof(float);  // ~4.2 MB
    if (ws_size >= ws_need) {
        float* wpart = (float*)d_ws;               // [512]
        float* part  = (float*)d_ws + 1024;        // [512][C]
        k_att<true><<<N / 16, 256, 0, stream>>>(x, attw, attb, xnew, part, wpart);
        k_centers<<<32, 256, 0, stream>>>(part, wpart, xnew);
    } else {                                        // atomic fallback
        float* wseg = (float*)d_ws;                // [4]
        k_zero<<<32, 256, 0, stream>>>(xnew, wseg);
        k_att<false><<<N / 16, 256, 0, stream>>>(x, attw, attb, xnew, nullptr, wseg);
        k_div<<<32, 256, 0, stream>>>(xnew, wseg);
    }
}